// Round 14
// baseline (102.885 us; speedup 1.0000x reference)
//
#include <hip/hip_runtime.h>
#include <hip/hip_bf16.h>

typedef short bf16x8 __attribute__((ext_vector_type(8)));
typedef short bf16x4 __attribute__((ext_vector_type(4)));
typedef float f32x4  __attribute__((ext_vector_type(4)));
typedef float f32x16 __attribute__((ext_vector_type(16)));

__device__ __forceinline__ unsigned short f2bf(float f) {
    union { float fv; unsigned int u; } v; v.fv = f;
    unsigned int r = v.u + 0x7FFFu + ((v.u >> 16) & 1u);
    return (unsigned short)(r >> 16);
}

__device__ __forceinline__ short f2bf_n(float f) {
    union { __hip_bfloat16 h; short s; } u;
    u.h = __float2bfloat16(f);
    return u.s;
}

__device__ __forceinline__ unsigned int cvtpk(float lo, float hi) {
    unsigned int r;
    asm volatile("v_cvt_pk_bf16_f32 %0, %1, %2" : "=v"(r) : "v"(lo), "v"(hi));
    return r;
}

__device__ __forceinline__ void gload16(const short* g, short* l) {
    __builtin_amdgcn_global_load_lds(
        (const __attribute__((address_space(1))) void*)g,
        (__attribute__((address_space(3))) void*)l, 16, 0, 0);
}

// ---- weights prep: tiled transpose f32 [K][N] -> bf16 [N][K] ----
__global__ __launch_bounds__(256) void tr_w2(
    const float* __restrict__ Wqkv, const float* __restrict__ Wout,
    short* __restrict__ Wqkvt, short* __restrict__ Woutt)
{
    __shared__ float tile[32][33];
    const int b = blockIdx.x;
    const float* src; short* dst; int N, bb;
    if (b < 768) { src = Wqkv; dst = Wqkvt; N = 1536; bb = b; }
    else         { src = Wout; dst = Woutt; N = 512;  bb = b - 768; }
    const int tx = threadIdx.x;
    const int nb = N >> 5;
    const int k0 = (bb / nb) * 32;
    const int n0 = (bb % nb) * 32;
    const int r  = tx >> 3;
    const int c4 = (tx & 7) * 4;
    f32x4 v = *(const f32x4*)(src + (size_t)(k0 + r) * N + n0 + c4);
    #pragma unroll
    for (int e = 0; e < 4; ++e) tile[r][c4 + e] = v[e];
    __syncthreads();
    bf16x4 o;
    #pragma unroll
    for (int e = 0; e < 4; ++e) o[e] = (short)f2bf(tile[c4 + e][r]);
    *(bf16x4*)(dst + (size_t)(n0 + r) * 512 + k0 + c4) = o;
}

// ---- GEMM with f32 A streamed in-kernel (T14 reg-staged A, gload_lds B) ----
// C[M,N](bf16) = cvt_bf16(A_f32[M,K]) * Bt[N,K]^T. Same LDS layout/swizzle and
// compute as gemm_db. Per tile: vmcnt(0) [ops issued one tile ago] ->
// cvt+ds_write A(t+1) -> issue B(t+1) gloads + A(t+2) f32 loads -> barrier.
__global__ __launch_bounds__(256, 2) void gemm_f32a(
    const float* __restrict__ A, const short* __restrict__ Bt,
    short* __restrict__ Cb, int M, int N, int K, int NB)
{
    __shared__ short lds[2][2][128 * 64];
    const int t    = threadIdx.x;
    const int lane = t & 63;
    const int wid  = t >> 6;
    const int l15  = lane & 15;
    const int lg   = lane >> 4;

    const int cpx = gridDim.x >> 3;
    const int swz = (blockIdx.x & 7) * cpx + (blockIdx.x >> 3);
    const int m0 = (swz / NB) * 128;
    const int n0 = (swz % NB) * 128;

    const int wm = (wid >> 1) * 64;
    const int wn = (wid & 1) * 64;

    const int srow = lane >> 3;
    const int scol = 8 * ((lane & 7) ^ ((lane >> 3) & 7));   // pre-swizzled chunk

    f32x4 acc[4][4];
    #pragma unroll
    for (int i = 0; i < 4; ++i)
        #pragma unroll
        for (int j = 0; j < 4; ++j)
            acc[i][j] = f32x4{0.f, 0.f, 0.f, 0.f};

    f32x4 areg[4][2];   // A(t+1) f32 in regs

    const int NT = K >> 6;   // 8

    auto loadA = [&](int tk) {
        #pragma unroll
        for (int j = 0; j < 4; ++j) {
            const float* src = A + (size_t)(m0 + wid * 32 + j * 8 + srow) * K
                               + tk * 64 + scol;
            areg[j][0] = *(const f32x4*)src;
            areg[j][1] = *(const f32x4*)(src + 4);
        }
    };
    auto writeA = [&](int buf) {
        #pragma unroll
        for (int j = 0; j < 4; ++j) {
            bf16x8 s;
            #pragma unroll
            for (int e = 0; e < 4; ++e) {
                s[e]     = (short)f2bf(areg[j][0][e]);
                s[4 + e] = (short)f2bf(areg[j][1][e]);
            }
            *(bf16x8*)&lds[buf][0][(wid * 32 + j * 8 + srow) * 64 + (lane & 7) * 8] = s;
        }
    };
    auto stageB = [&](int buf, int tk) {
        #pragma unroll
        for (int j = 0; j < 4; ++j)
            gload16(Bt + (size_t)(n0 + wid * 32 + j * 8 + srow) * K + tk * 64 + scol,
                    &lds[buf][1][(wid * 32 + j * 8) * 64]);
    };

    // prologue: A0 -> regs -> LDS[0]; B0 -> LDS[0]; A1 -> regs
    loadA(0);                                              // 8 vmem
    stageB(0, 0);                                          // 4 vmem
    asm volatile("s_waitcnt vmcnt(4)" ::: "memory");       // A0 landed
    writeA(0);
    loadA(1);                                              // 8 vmem
    asm volatile("s_waitcnt vmcnt(8) lgkmcnt(0)" ::: "memory");  // B0 + ds_writes
    __builtin_amdgcn_s_barrier();

    for (int tk = 0; tk < NT; ++tk) {
        const int cur = tk & 1;
        if (tk + 1 < NT) {
            asm volatile("s_waitcnt vmcnt(0)" ::: "memory");   // B(tk)+A(tk+1), issued 1 tile ago
            writeA(cur ^ 1);
            stageB(cur ^ 1, tk + 1);
            if (tk + 2 < NT) loadA(tk + 2);
            asm volatile("s_waitcnt lgkmcnt(0)" ::: "memory"); // ds_writes visible
        } else {
            asm volatile("s_waitcnt vmcnt(0)" ::: "memory");
        }
        __builtin_amdgcn_s_barrier();

        bf16x8 af[4][2], bg[4][2];
        #pragma unroll
        for (int kk = 0; kk < 2; ++kk) {
            #pragma unroll
            for (int mi = 0; mi < 4; ++mi)
                af[mi][kk] = *(const bf16x8*)&lds[cur][0][
                    (wm + mi * 16 + l15) * 64 + (((kk * 4 + lg) ^ (l15 & 7)) * 8)];
            #pragma unroll
            for (int ni = 0; ni < 4; ++ni)
                bg[ni][kk] = *(const bf16x8*)&lds[cur][1][
                    (wn + ni * 16 + l15) * 64 + (((kk * 4 + lg) ^ (l15 & 7)) * 8)];
        }

        __builtin_amdgcn_s_setprio(1);
        #pragma unroll
        for (int kk = 0; kk < 2; ++kk)
            #pragma unroll
            for (int mi = 0; mi < 4; ++mi)
                #pragma unroll
                for (int ni = 0; ni < 4; ++ni)
                    acc[mi][ni] = __builtin_amdgcn_mfma_f32_16x16x32_bf16(
                        af[mi][kk], bg[ni][kk], acc[mi][ni], 0, 0, 0);
        __builtin_amdgcn_s_setprio(0);
        __builtin_amdgcn_s_barrier();
    }

    #pragma unroll
    for (int mi = 0; mi < 4; ++mi) {
        #pragma unroll
        for (int ni = 0; ni < 4; ++ni) {
            const int col = n0 + wn + ni * 16 + l15;
            #pragma unroll
            for (int r = 0; r < 4; ++r) {
                const int rowi = m0 + wm + mi * 16 + 4 * lg + r;
                Cb[(size_t)rowi * N + col] = (short)f2bf(acc[mi][ni][r]);
            }
        }
    }
}

// ---- GEMM (bf16 A): 128x128, dbuf LDS, counted vmcnt prefetch ----
template<int F32OUT>
__global__ __launch_bounds__(256, 2) void gemm_db(
    const short* __restrict__ A, const short* __restrict__ Bt,
    short* __restrict__ Cb, float* __restrict__ Cf, const float* __restrict__ bias,
    int M, int N, int K, int NB)
{
    __shared__ short lds[2][2][128 * 64];
    const int t    = threadIdx.x;
    const int lane = t & 63;
    const int wid  = t >> 6;
    const int l15  = lane & 15;
    const int lg   = lane >> 4;

    const int cpx = gridDim.x >> 3;
    const int swz = (blockIdx.x & 7) * cpx + (blockIdx.x >> 3);
    const int m0 = (swz / NB) * 128;
    const int n0 = (swz % NB) * 128;

    const int wm = (wid >> 1) * 64;
    const int wn = (wid & 1) * 64;

    const int scol = 8 * ((lane & 7) ^ ((lane >> 3) & 7));

    float bval[4];
    if constexpr (F32OUT) {
        #pragma unroll
        for (int ni = 0; ni < 4; ++ni) bval[ni] = bias[n0 + wn + ni * 16 + l15];
    }

    f32x4 acc[4][4];
    #pragma unroll
    for (int i = 0; i < 4; ++i)
        #pragma unroll
        for (int j = 0; j < 4; ++j)
            acc[i][j] = f32x4{0.f, 0.f, 0.f, 0.f};

    const int NT = K >> 6;

    auto stage = [&](int buf, int tk) {
        #pragma unroll
        for (int j = 0; j < 4; ++j) {
            const int r = wid * 32 + j * 8 + (lane >> 3);
            gload16(A  + (size_t)(m0 + r) * K + tk * 64 + scol,
                    &lds[buf][0][(wid * 32 + j * 8) * 64]);
            gload16(Bt + (size_t)(n0 + r) * K + tk * 64 + scol,
                    &lds[buf][1][(wid * 32 + j * 8) * 64]);
        }
    };

    stage(0, 0);

    for (int tk = 0; tk < NT; ++tk) {
        const int cur = tk & 1;
        if (tk + 1 < NT) {
            stage(cur ^ 1, tk + 1);
            asm volatile("s_waitcnt vmcnt(8)" ::: "memory");
        } else {
            asm volatile("s_waitcnt vmcnt(0)" ::: "memory");
        }
        __builtin_amdgcn_s_barrier();

        bf16x8 af[4][2], bg[4][2];
        #pragma unroll
        for (int kk = 0; kk < 2; ++kk) {
            #pragma unroll
            for (int mi = 0; mi < 4; ++mi)
                af[mi][kk] = *(const bf16x8*)&lds[cur][0][
                    (wm + mi * 16 + l15) * 64 + (((kk * 4 + lg) ^ (l15 & 7)) * 8)];
            #pragma unroll
            for (int ni = 0; ni < 4; ++ni)
                bg[ni][kk] = *(const bf16x8*)&lds[cur][1][
                    (wn + ni * 16 + l15) * 64 + (((kk * 4 + lg) ^ (l15 & 7)) * 8)];
        }

        __builtin_amdgcn_s_setprio(1);
        #pragma unroll
        for (int kk = 0; kk < 2; ++kk)
            #pragma unroll
            for (int mi = 0; mi < 4; ++mi)
                #pragma unroll
                for (int ni = 0; ni < 4; ++ni)
                    acc[mi][ni] = __builtin_amdgcn_mfma_f32_16x16x32_bf16(
                        af[mi][kk], bg[ni][kk], acc[mi][ni], 0, 0, 0);
        __builtin_amdgcn_s_setprio(0);
        __builtin_amdgcn_s_barrier();
    }

    #pragma unroll
    for (int mi = 0; mi < 4; ++mi) {
        #pragma unroll
        for (int ni = 0; ni < 4; ++ni) {
            const int col = n0 + wn + ni * 16 + l15;
            #pragma unroll
            for (int r = 0; r < 4; ++r) {
                const int rowi = m0 + wm + mi * 16 + 4 * lg + r;
                if constexpr (F32OUT) {
                    Cf[(size_t)rowi * N + col] = acc[mi][ni][r] + bval[ni];
                } else {
                    Cb[(size_t)rowi * N + col] = (short)f2bf(acc[mi][ni][r]);
                }
            }
        }
    }
}

// ---- fused attention (R13-verified): 32x32 MFMA + in-lane softmax ----
__global__ __launch_bounds__(512, 4) void attn_kernel(
    const short* __restrict__ qkv, short* __restrict__ attn_out)
{
    __shared__ short Kl[2][4096];    // [kv][64] linear, chunk-swizzled
    __shared__ short Vt[2][5120];    // [d][80] octet-swizzled
    const int t    = threadIdx.x;
    const int lane = t & 63;
    const int wid  = t >> 6;
    const int l31  = lane & 31;
    const int hi   = lane >> 5;
    const int pairid = blockIdx.x & 255;
    const int qh  = blockIdx.x >> 8;
    const int bp  = pairid >> 3;
    const int h   = pairid & 7;
    const size_t tok0 = (size_t)bp * 512;
    const int q0   = qh * 256 + wid * 32;
    const int qcol = h * 64;

    bf16x8 qf[4];
    #pragma unroll
    for (int kf = 0; kf < 4; ++kf)
        qf[kf] = *(const bf16x8*)(qkv + (tok0 + q0 + l31) * 1536
                                  + qcol + kf * 16 + 8 * hi);

    f32x16 ot0, ot1;
    #pragma unroll
    for (int r = 0; r < 16; ++r) { ot0[r] = 0.f; ot1[r] = 0.f; }
    float mrun = -1e30f, lrun = 0.f;

    const int krow = t >> 3;
    const short* Ksrc0 = qkv + (tok0 + krow) * 1536 + 512 + qcol
                         + 8 * ((t & 7) ^ (krow & 7));
    const int sn = t >> 3;
    const int sd = (t & 7) * 8;
    const short* Vsrc0 = qkv + (tok0 + sn) * 1536 + 1024 + qcol + sd;
    const int kvp = (sn & 7) | (((sn >> 3) ^ (t & 7)) << 3);

    gload16(Ksrc0, &Kl[0][t * 8]);
    bf16x8 vreg = *(const bf16x8*)(Vsrc0);

    const float C = 0.18033688011112042f;   // 0.125 * log2(e)

    for (int tkv = 0; tkv < 8; ++tkv) {
        const int cur = tkv & 1;
        #pragma unroll
        for (int i = 0; i < 8; ++i)
            Vt[cur][(sd + i) * 80 + kvp] = vreg[i];
        __syncthreads();
        if (tkv < 7) {
            gload16(Ksrc0 + (size_t)(tkv + 1) * 64 * 1536, &Kl[cur ^ 1][t * 8]);
            vreg = *(const bf16x8*)(Vsrc0 + (size_t)(tkv + 1) * 64 * 1536);
        }

        f32x16 st0, st1;
        #pragma unroll
        for (int r = 0; r < 16; ++r) { st0[r] = 0.f; st1[r] = 0.f; }
        __builtin_amdgcn_s_setprio(1);
        #pragma unroll
        for (int kf = 0; kf < 4; ++kf) {
            const int slot = ((2 * kf + hi) ^ (l31 & 7)) * 8;
            bf16x8 k0 = *(const bf16x8*)&Kl[cur][l31 * 64 + slot];
            bf16x8 k1 = *(const bf16x8*)&Kl[cur][(32 + l31) * 64 + slot];
            st0 = __builtin_amdgcn_mfma_f32_32x32x16_bf16(k0, qf[kf], st0, 0, 0, 0);
            st1 = __builtin_amdgcn_mfma_f32_32x32x16_bf16(k1, qf[kf], st1, 0, 0, 0);
        }
        __builtin_amdgcn_s_setprio(0);

        float pm = st0[0];
        #pragma unroll
        for (int r = 1; r < 16; ++r) pm = fmaxf(pm, st0[r]);
        #pragma unroll
        for (int r = 0; r < 16; ++r) pm = fmaxf(pm, st1[r]);
        pm = fmaxf(pm, __shfl_xor(pm, 32));
        pm *= C;
        if (!__all(pm <= mrun + 8.f)) {
            const float mnew = fmaxf(mrun, pm);
            const float fsc  = __builtin_amdgcn_exp2f(mrun - mnew);
            lrun *= fsc;
            #pragma unroll
            for (int r = 0; r < 16; ++r) { ot0[r] *= fsc; ot1[r] *= fsc; }
            mrun = mnew;
        }
        float ps = 0.f;
        #pragma unroll
        for (int r = 0; r < 16; ++r) {
            st0[r] = __builtin_amdgcn_exp2f(__builtin_fmaf(st0[r], C, -mrun));
            ps += st0[r];
        }
        #pragma unroll
        for (int r = 0; r < 16; ++r) {
            st1[r] = __builtin_amdgcn_exp2f(__builtin_fmaf(st1[r], C, -mrun));
            ps += st1[r];
        }
        ps += __shfl_xor(ps, 32);
        lrun += ps;

        __builtin_amdgcn_s_setprio(1);
#define PVKS(KS, ST)                                                          \
        {                                                                     \
            const int a8 = ((KS) & 1) * 8;                                    \
            unsigned int s0a = cvtpk(ST[a8 + 0], ST[a8 + 1]);                 \
            unsigned int s0b = cvtpk(ST[a8 + 2], ST[a8 + 3]);                 \
            unsigned int s1a = cvtpk(ST[a8 + 4], ST[a8 + 5]);                 \
            unsigned int s1b = cvtpk(ST[a8 + 6], ST[a8 + 7]);                 \
            asm volatile("v_permlane32_swap_b32 %0, %1"                       \
                         : "+v"(s0a), "+v"(s1a));                             \
            asm volatile("v_permlane32_swap_b32 %0, %1"                       \
                         : "+v"(s0b), "+v"(s1b));                             \
            union { unsigned int w[4]; bf16x8 v; } pu;                        \
            pu.w[0] = s0a; pu.w[1] = s0b; pu.w[2] = s1a; pu.w[3] = s1b;       \
            {                                                                 \
                const int sl0 = ((2 * (KS) + hi) ^ (l31 >> 3)) * 8;           \
                bf16x8 vf = *(const bf16x8*)&Vt[cur][l31 * 80 + sl0];         \
                ot0 = __builtin_amdgcn_mfma_f32_32x32x16_bf16(                \
                    vf, pu.v, ot0, 0, 0, 0);                                  \
            }                                                                 \
            {                                                                 \
                const int sl1 = ((2 * (KS) + hi) ^ (4 ^ (l31 >> 3))) * 8;     \
                bf16x8 vf = *(const bf16x8*)&Vt[cur][(32 + l31) * 80 + sl1];  \
                ot1 = __builtin_amdgcn_mfma_f32_32x32x16_bf16(                \
                    vf, pu.v, ot1, 0, 0, 0);                                  \
            }                                                                 \
        }
        PVKS(0, st0)
        PVKS(1, st0)
        PVKS(2, st1)
        PVKS(3, st1)
#undef PVKS
        __builtin_amdgcn_s_setprio(0);
    }

    const float inv = 1.f / lrun;
    short* obase = attn_out + (tok0 + q0 + l31) * 512 + qcol + 4 * hi;
    #pragma unroll
    for (int rq = 0; rq < 4; ++rq) {
        bf16x4 o0, o1;
        #pragma unroll
        for (int j = 0; j < 4; ++j) {
            o0[j] = f2bf_n(ot0[4 * rq + j] * inv);
            o1[j] = f2bf_n(ot1[4 * rq + j] * inv);
        }
        *(bf16x4*)(obase + rq * 8)      = o0;
        *(bf16x4*)(obase + 32 + rq * 8) = o1;
    }
}

extern "C" void kernel_launch(void* const* d_in, const int* in_sizes, int n_in,
                              void* d_out, int out_size, void* d_ws, size_t ws_size,
                              hipStream_t stream) {
    const float* x    = (const float*)d_in[0];   // [16384][512]
    const float* Wqkv = (const float*)d_in[1];   // [512][1536]
    const float* Wout = (const float*)d_in[2];   // [512][512]
    const float* bout = (const float*)d_in[3];   // [512]
    float* out = (float*)d_out;                  // [16384][512] f32

    char* ws = (char*)d_ws;
    short* qkvb  = (short*)(ws);                 // 48 MB  [16384][1536] bf16
    short* attnb = (short*)(ws + 50331648ull);   // 16 MB  [16384][512]  bf16
    short* Wqkvt = (short*)(ws + 67108864ull);   // 1.5 MB [1536][512]   bf16
    short* Woutt = (short*)(ws + 68681728ull);   // 0.5 MB [512][512]    bf16

    tr_w2<<<1024, 256, 0, stream>>>(Wqkv, Wout, Wqkvt, Woutt);

    // QKV: f32 A streamed, M=16384 (128 mb) x N=1536 (12 nb), N fastest
    gemm_f32a<<<1536, 256, 0, stream>>>(x, Wqkvt, qkvb, 16384, 1536, 512, 12);

    attn_kernel<<<512, 512, 0, stream>>>(qkvb, attnb);

    // out-proj: M=16384 x N=512 (4 nb)
    gemm_db<1><<<512, 256, 0, stream>>>(attnb, Woutt, nullptr, out, bout,
                                        16384, 512, 512, 4);
}

// Round 15
// 91.602 us; speedup vs baseline: 1.1232x; 1.1232x over previous
//
#include <hip/hip_runtime.h>
#include <hip/hip_bf16.h>

typedef short bf16x8 __attribute__((ext_vector_type(8)));
typedef short bf16x4 __attribute__((ext_vector_type(4)));
typedef float f32x4  __attribute__((ext_vector_type(4)));
typedef float f32x16 __attribute__((ext_vector_type(16)));

__device__ __forceinline__ unsigned short f2bf(float f) {
    union { float fv; unsigned int u; } v; v.fv = f;
    unsigned int r = v.u + 0x7FFFu + ((v.u >> 16) & 1u);
    return (unsigned short)(r >> 16);
}

__device__ __forceinline__ short f2bf_n(float f) {
    union { __hip_bfloat16 h; short s; } u;
    u.h = __float2bfloat16(f);
    return u.s;
}

__device__ __forceinline__ unsigned int cvtpk(float lo, float hi) {
    unsigned int r;
    asm volatile("v_cvt_pk_bf16_f32 %0, %1, %2" : "=v"(r) : "v"(lo), "v"(hi));
    return r;
}

__device__ __forceinline__ void gload16(const short* g, short* l) {
    __builtin_amdgcn_global_load_lds(
        (const __attribute__((address_space(1))) void*)g,
        (__attribute__((address_space(3))) void*)l, 16, 0, 0);
}

// ---- merged prep: blocks 0..4095 convert x f32->bf16 (8 elems/thread);
//      blocks 4096..5119 transpose+convert the two weight matrices ----
__global__ __launch_bounds__(256) void prep_all(
    const float* __restrict__ x, short* __restrict__ xb,
    const float* __restrict__ Wqkv, const float* __restrict__ Wout,
    short* __restrict__ Wqkvt, short* __restrict__ Woutt)
{
    if (blockIdx.x < 4096) {
        size_t i = ((size_t)blockIdx.x * 256 + threadIdx.x) * 8;
        f32x4 a = *(const f32x4*)(x + i);
        f32x4 b = *(const f32x4*)(x + i + 4);
        bf16x8 s;
        #pragma unroll
        for (int e = 0; e < 4; ++e) { s[e] = (short)f2bf(a[e]); s[4 + e] = (short)f2bf(b[e]); }
        *(bf16x8*)(xb + i) = s;
        return;
    }
    __shared__ float tile[32][33];
    const int b = blockIdx.x - 4096;
    const float* src; short* dst; int N, bb;
    if (b < 768) { src = Wqkv; dst = Wqkvt; N = 1536; bb = b; }
    else         { src = Wout; dst = Woutt; N = 512;  bb = b - 768; }
    const int tx = threadIdx.x;
    const int nb = N >> 5;
    const int k0 = (bb / nb) * 32;
    const int n0 = (bb % nb) * 32;
    const int r  = tx >> 3;
    const int c4 = (tx & 7) * 4;
    f32x4 v = *(const f32x4*)(src + (size_t)(k0 + r) * N + n0 + c4);
    #pragma unroll
    for (int e = 0; e < 4; ++e) tile[r][c4 + e] = v[e];
    __syncthreads();
    bf16x4 o;
    #pragma unroll
    for (int e = 0; e < 4; ++e) o[e] = (short)f2bf(tile[c4 + e][r]);
    *(bf16x4*)(dst + (size_t)(n0 + r) * 512 + k0 + c4) = o;
}

// ---- GEMM: 128x128 tile, double-buffered LDS, counted vmcnt prefetch ----
template<int F32OUT>
__global__ __launch_bounds__(256, 2) void gemm_db(
    const short* __restrict__ A, const short* __restrict__ Bt,
    short* __restrict__ Cb, float* __restrict__ Cf, const float* __restrict__ bias,
    int M, int N, int K, int NB)
{
    __shared__ short lds[2][2][128 * 64];   // [buf][A|B][row*64+chunk*8]
    const int t    = threadIdx.x;
    const int lane = t & 63;
    const int wid  = t >> 6;
    const int l15  = lane & 15;
    const int lg   = lane >> 4;

    const int cpx = gridDim.x >> 3;
    const int swz = (blockIdx.x & 7) * cpx + (blockIdx.x >> 3);
    const int m0 = (swz / NB) * 128;
    const int n0 = (swz % NB) * 128;

    const int wm = (wid >> 1) * 64;
    const int wn = (wid & 1) * 64;

    const int scol = 8 * ((lane & 7) ^ ((lane >> 3) & 7));

    float bval[4];
    if constexpr (F32OUT) {
        #pragma unroll
        for (int ni = 0; ni < 4; ++ni) bval[ni] = bias[n0 + wn + ni * 16 + l15];
    }

    f32x4 acc[4][4];
    #pragma unroll
    for (int i = 0; i < 4; ++i)
        #pragma unroll
        for (int j = 0; j < 4; ++j)
            acc[i][j] = f32x4{0.f, 0.f, 0.f, 0.f};

    const int NT = K >> 6;

    auto stage = [&](int buf, int tk) {
        #pragma unroll
        for (int j = 0; j < 4; ++j) {
            const int r = wid * 32 + j * 8 + (lane >> 3);
            gload16(A  + (size_t)(m0 + r) * K + tk * 64 + scol,
                    &lds[buf][0][(wid * 32 + j * 8) * 64]);
            gload16(Bt + (size_t)(n0 + r) * K + tk * 64 + scol,
                    &lds[buf][1][(wid * 32 + j * 8) * 64]);
        }
    };

    stage(0, 0);

    for (int tk = 0; tk < NT; ++tk) {
        const int cur = tk & 1;
        if (tk + 1 < NT) {
            stage(cur ^ 1, tk + 1);
            asm volatile("s_waitcnt vmcnt(8)" ::: "memory");
        } else {
            asm volatile("s_waitcnt vmcnt(0)" ::: "memory");
        }
        __builtin_amdgcn_s_barrier();

        bf16x8 af[4][2], bg[4][2];
        #pragma unroll
        for (int kk = 0; kk < 2; ++kk) {
            #pragma unroll
            for (int mi = 0; mi < 4; ++mi)
                af[mi][kk] = *(const bf16x8*)&lds[cur][0][
                    (wm + mi * 16 + l15) * 64 + (((kk * 4 + lg) ^ (l15 & 7)) * 8)];
            #pragma unroll
            for (int ni = 0; ni < 4; ++ni)
                bg[ni][kk] = *(const bf16x8*)&lds[cur][1][
                    (wn + ni * 16 + l15) * 64 + (((kk * 4 + lg) ^ (l15 & 7)) * 8)];
        }

        __builtin_amdgcn_s_setprio(1);
        #pragma unroll
        for (int kk = 0; kk < 2; ++kk)
            #pragma unroll
            for (int mi = 0; mi < 4; ++mi)
                #pragma unroll
                for (int ni = 0; ni < 4; ++ni)
                    acc[mi][ni] = __builtin_amdgcn_mfma_f32_16x16x32_bf16(
                        af[mi][kk], bg[ni][kk], acc[mi][ni], 0, 0, 0);
        __builtin_amdgcn_s_setprio(0);
        __builtin_amdgcn_s_barrier();
    }

    #pragma unroll
    for (int mi = 0; mi < 4; ++mi) {
        #pragma unroll
        for (int ni = 0; ni < 4; ++ni) {
            const int col = n0 + wn + ni * 16 + l15;
            #pragma unroll
            for (int r = 0; r < 4; ++r) {
                const int rowi = m0 + wm + mi * 16 + 4 * lg + r;
                if constexpr (F32OUT) {
                    Cf[(size_t)rowi * N + col] = acc[mi][ni][r] + bval[ni];
                } else {
                    Cb[(size_t)rowi * N + col] = (short)f2bf(acc[mi][ni][r]);
                }
            }
        }
    }
}

// ---- fused attention (R13-verified): 32x32 MFMA + in-lane softmax ----
// Lane holds q = lane&31; lanes l / l+32 hold the two kv-halves (hi = lane>>5).
// permlane32_swap HW semantics (LLVM): vdst.lanes[32:63] <-> vsrc.lanes[0:31].
// P B-frag per K=16 slice: swap(vdst=s0a, vsrc=s1a) -> s0a = w0, s1a = w2.
// Reduces use __shfl_xor(.,32) — no register-aliasing hazard.
__global__ __launch_bounds__(512, 4) void attn_kernel(
    const short* __restrict__ qkv, short* __restrict__ attn_out)
{
    __shared__ short Kl[2][4096];    // [kv][64] linear, chunk-swizzled
    __shared__ short Vt[2][5120];    // [d][80] octet-swizzled
    const int t    = threadIdx.x;
    const int lane = t & 63;
    const int wid  = t >> 6;
    const int l31  = lane & 31;
    const int hi   = lane >> 5;
    const int pairid = blockIdx.x & 255;
    const int qh  = blockIdx.x >> 8;
    const int bp  = pairid >> 3;
    const int h   = pairid & 7;
    const size_t tok0 = (size_t)bp * 512;
    const int q0   = qh * 256 + wid * 32;
    const int qcol = h * 64;

    bf16x8 qf[4];
    #pragma unroll
    for (int kf = 0; kf < 4; ++kf)
        qf[kf] = *(const bf16x8*)(qkv + (tok0 + q0 + l31) * 1536
                                  + qcol + kf * 16 + 8 * hi);

    f32x16 ot0, ot1;
    #pragma unroll
    for (int r = 0; r < 16; ++r) { ot0[r] = 0.f; ot1[r] = 0.f; }
    float mrun = -1e30f, lrun = 0.f;

    const int krow = t >> 3;
    const short* Ksrc0 = qkv + (tok0 + krow) * 1536 + 512 + qcol
                         + 8 * ((t & 7) ^ (krow & 7));
    const int sn = t >> 3;
    const int sd = (t & 7) * 8;
    const short* Vsrc0 = qkv + (tok0 + sn) * 1536 + 1024 + qcol + sd;
    const int kvp = (sn & 7) | (((sn >> 3) ^ (t & 7)) << 3);

    gload16(Ksrc0, &Kl[0][t * 8]);
    bf16x8 vreg = *(const bf16x8*)(Vsrc0);

    const float C = 0.18033688011112042f;   // 0.125 * log2(e)

    for (int tkv = 0; tkv < 8; ++tkv) {
        const int cur = tkv & 1;
        #pragma unroll
        for (int i = 0; i < 8; ++i)
            Vt[cur][(sd + i) * 80 + kvp] = vreg[i];
        __syncthreads();
        if (tkv < 7) {
            gload16(Ksrc0 + (size_t)(tkv + 1) * 64 * 1536, &Kl[cur ^ 1][t * 8]);
            vreg = *(const bf16x8*)(Vsrc0 + (size_t)(tkv + 1) * 64 * 1536);
        }

        f32x16 st0, st1;
        #pragma unroll
        for (int r = 0; r < 16; ++r) { st0[r] = 0.f; st1[r] = 0.f; }
        __builtin_amdgcn_s_setprio(1);
        #pragma unroll
        for (int kf = 0; kf < 4; ++kf) {
            const int slot = ((2 * kf + hi) ^ (l31 & 7)) * 8;
            bf16x8 k0 = *(const bf16x8*)&Kl[cur][l31 * 64 + slot];
            bf16x8 k1 = *(const bf16x8*)&Kl[cur][(32 + l31) * 64 + slot];
            st0 = __builtin_amdgcn_mfma_f32_32x32x16_bf16(k0, qf[kf], st0, 0, 0, 0);
            st1 = __builtin_amdgcn_mfma_f32_32x32x16_bf16(k1, qf[kf], st1, 0, 0, 0);
        }
        __builtin_amdgcn_s_setprio(0);

        float pm = st0[0];
        #pragma unroll
        for (int r = 1; r < 16; ++r) pm = fmaxf(pm, st0[r]);
        #pragma unroll
        for (int r = 0; r < 16; ++r) pm = fmaxf(pm, st1[r]);
        pm = fmaxf(pm, __shfl_xor(pm, 32));
        pm *= C;
        if (!__all(pm <= mrun + 8.f)) {
            const float mnew = fmaxf(mrun, pm);
            const float fsc  = __builtin_amdgcn_exp2f(mrun - mnew);
            lrun *= fsc;
            #pragma unroll
            for (int r = 0; r < 16; ++r) { ot0[r] *= fsc; ot1[r] *= fsc; }
            mrun = mnew;
        }
        float ps = 0.f;
        #pragma unroll
        for (int r = 0; r < 16; ++r) {
            st0[r] = __builtin_amdgcn_exp2f(__builtin_fmaf(st0[r], C, -mrun));
            ps += st0[r];
        }
        #pragma unroll
        for (int r = 0; r < 16; ++r) {
            st1[r] = __builtin_amdgcn_exp2f(__builtin_fmaf(st1[r], C, -mrun));
            ps += st1[r];
        }
        ps += __shfl_xor(ps, 32);
        lrun += ps;

        __builtin_amdgcn_s_setprio(1);
#define PVKS(KS, ST)                                                          \
        {                                                                     \
            const int a8 = ((KS) & 1) * 8;                                    \
            unsigned int s0a = cvtpk(ST[a8 + 0], ST[a8 + 1]);                 \
            unsigned int s0b = cvtpk(ST[a8 + 2], ST[a8 + 3]);                 \
            unsigned int s1a = cvtpk(ST[a8 + 4], ST[a8 + 5]);                 \
            unsigned int s1b = cvtpk(ST[a8 + 6], ST[a8 + 7]);                 \
            asm volatile("v_permlane32_swap_b32 %0, %1"                       \
                         : "+v"(s0a), "+v"(s1a));                             \
            asm volatile("v_permlane32_swap_b32 %0, %1"                       \
                         : "+v"(s0b), "+v"(s1b));                             \
            union { unsigned int w[4]; bf16x8 v; } pu;                        \
            pu.w[0] = s0a; pu.w[1] = s0b; pu.w[2] = s1a; pu.w[3] = s1b;       \
            {                                                                 \
                const int sl0 = ((2 * (KS) + hi) ^ (l31 >> 3)) * 8;           \
                bf16x8 vf = *(const bf16x8*)&Vt[cur][l31 * 80 + sl0];         \
                ot0 = __builtin_amdgcn_mfma_f32_32x32x16_bf16(                \
                    vf, pu.v, ot0, 0, 0, 0);                                  \
            }                                                                 \
            {                                                                 \
                const int sl1 = ((2 * (KS) + hi) ^ (4 ^ (l31 >> 3))) * 8;     \
                bf16x8 vf = *(const bf16x8*)&Vt[cur][(32 + l31) * 80 + sl1];  \
                ot1 = __builtin_amdgcn_mfma_f32_32x32x16_bf16(                \
                    vf, pu.v, ot1, 0, 0, 0);                                  \
            }                                                                 \
        }
        PVKS(0, st0)
        PVKS(1, st0)
        PVKS(2, st1)
        PVKS(3, st1)
#undef PVKS
        __builtin_amdgcn_s_setprio(0);
    }

    const float inv = 1.f / lrun;
    short* obase = attn_out + (tok0 + q0 + l31) * 512 + qcol + 4 * hi;
    #pragma unroll
    for (int rq = 0; rq < 4; ++rq) {
        bf16x4 o0, o1;
        #pragma unroll
        for (int j = 0; j < 4; ++j) {
            o0[j] = f2bf_n(ot0[4 * rq + j] * inv);
            o1[j] = f2bf_n(ot1[4 * rq + j] * inv);
        }
        *(bf16x4*)(obase + rq * 8)      = o0;
        *(bf16x4*)(obase + 32 + rq * 8) = o1;
    }
}

extern "C" void kernel_launch(void* const* d_in, const int* in_sizes, int n_in,
                              void* d_out, int out_size, void* d_ws, size_t ws_size,
                              hipStream_t stream) {
    const float* x    = (const float*)d_in[0];   // [16384][512]
    const float* Wqkv = (const float*)d_in[1];   // [512][1536]
    const float* Wout = (const float*)d_in[2];   // [512][512]
    const float* bout = (const float*)d_in[3];   // [512]
    float* out = (float*)d_out;                  // [16384][512] f32

    char* ws = (char*)d_ws;
    short* qkvb  = (short*)(ws);                 // 48 MB  [16384][1536] bf16
    short* xb    = (short*)(ws + 50331648ull);   // 16 MB  [16384][512]  bf16 (x)
    short* attnb = xb;                           // reuse: xb dead before attn writes
    short* Wqkvt = (short*)(ws + 67108864ull);   // 1.5 MB [1536][512]   bf16
    short* Woutt = (short*)(ws + 68681728ull);   // 0.5 MB [512][512]    bf16

    prep_all<<<5120, 256, 0, stream>>>(x, xb, Wqkv, Wout, Wqkvt, Woutt);

    // M=16384 (128 mb) x N=1536 (12 nb) -> 1536 blocks (N fastest)
    gemm_db<0><<<1536, 256, 0, stream>>>(xb, Wqkvt, qkvb, nullptr, nullptr,
                                         16384, 1536, 512, 12);

    attn_kernel<<<512, 512, 0, stream>>>(qkvb, attnb);

    // M=16384 (128 mb) x N=512 (4 nb) -> 512 blocks
    gemm_db<1><<<512, 256, 0, stream>>>(attnb, Woutt, nullptr, out, bout,
                                        16384, 512, 512, 4);
}